// Round 11
// baseline (296.246 us; speedup 1.0000x reference)
//
#include <hip/hip_runtime.h>

#define B_ 8
#define T_ 4096
#define E_ 1024
#define K_ 128

typedef __bf16 bf16;
typedef bf16 bf16x8 __attribute__((ext_vector_type(8)));
typedef bf16 bf16x4 __attribute__((ext_vector_type(4)));
typedef float f32x4 __attribute__((ext_vector_type(4)));

// ---------------- K0: convert mu to bf16 ----------------
__global__ __launch_bounds__(256) void k0_cvt_mu(const float* __restrict__ mu,
                                                 bf16* __restrict__ mub) {
    int i = blockIdx.x * 256 + threadIdx.x;
    mub[i] = (bf16)mu[i];
}

// ---------------- K1: attP[h,b,k,t] = sum_{e in half h} mu[k,e]*x[b,t,e]; also xb=(bf16)x ----
// grid (T/64, 2, B) = 1024 blocks, 256 thr (4 waves). Wave: 16 t x 128 k.  [round-9 proven]
__global__ __launch_bounds__(256) void k1_att(const float* __restrict__ x,
                                              const bf16* __restrict__ mub,
                                              float* __restrict__ attP,
                                              bf16* __restrict__ xb) {
    const int b = blockIdx.z;
    const int h = blockIdx.y;
    const int w = threadIdx.x >> 6, lane = threadIdx.x & 63;
    const int g = lane >> 4, ln = lane & 15;
    const int t = blockIdx.x * 64 + w * 16 + ln;

    f32x4 acc[8];
#pragma unroll
    for (int m = 0; m < 8; ++m) acc[m] = (f32x4){0.f, 0.f, 0.f, 0.f};

    const float* xrow = x + ((size_t)b * T_ + t) * E_ + h * 512 + g * 8;
    bf16* xbrow = xb + ((size_t)b * T_ + t) * E_ + h * 512 + g * 8;
    const bf16* mu0 = mub + h * 512 + g * 8;
#pragma unroll 2
    for (int e0 = 0; e0 < 512; e0 += 32) {
        f32x4 u0 = *(const f32x4*)(xrow + e0);
        f32x4 u1 = *(const f32x4*)(xrow + e0 + 4);
        bf16x8 af[8];
#pragma unroll
        for (int m = 0; m < 8; ++m)
            af[m] = *(const bf16x8*)(mu0 + (size_t)(m * 16 + ln) * E_ + e0);
        bf16x8 bf;
        bf[0] = (bf16)u0[0]; bf[1] = (bf16)u0[1]; bf[2] = (bf16)u0[2]; bf[3] = (bf16)u0[3];
        bf[4] = (bf16)u1[0]; bf[5] = (bf16)u1[1]; bf[6] = (bf16)u1[2]; bf[7] = (bf16)u1[3];
        *(bf16x8*)(xbrow + e0) = bf;
#pragma unroll
        for (int m = 0; m < 8; ++m)
            acc[m] = __builtin_amdgcn_mfma_f32_16x16x32_bf16(af[m], bf, acc[m], 0, 0, 0);
    }
#pragma unroll
    for (int m = 0; m < 8; ++m)
#pragma unroll
        for (int r = 0; r < 4; ++r)
            attP[(((size_t)h * B_ + b) * K_ + m * 16 + g * 4 + r) * T_ + t] = acc[m][r];
}

// ---------------- K2: fused half-sum + softmax -> attp bf16 AND attpT bf16 ----------------
// grid 1024 blocks (one per b,k row).
__global__ __launch_bounds__(256) void k2_softmax(const float* __restrict__ attP,
                                                  bf16* __restrict__ attp,
                                                  bf16* __restrict__ attpT) {
    const int row = blockIdx.x;   // b*K + k
    const int b = row >> 7;
    const int kk_ = row & 127;
    const int tid = threadIdx.x;
    const f32x4* p0 = (const f32x4*)(attP + (size_t)row * T_);
    const f32x4* p1 = (const f32x4*)(attP + ((size_t)(B_ * K_) + row) * T_);
    f32x4 v[4];
    float m = -1e30f;
#pragma unroll
    for (int i = 0; i < 4; ++i) {
        f32x4 a = p0[i * 256 + tid];
        f32x4 c = p1[i * 256 + tid];
        v[i] = (a + c) * 0.03125f;
        m = fmaxf(m, fmaxf(fmaxf(v[i][0], v[i][1]), fmaxf(v[i][2], v[i][3])));
    }
#pragma unroll
    for (int off = 32; off > 0; off >>= 1) m = fmaxf(m, __shfl_xor(m, off));
    __shared__ float redm[4], reds[4];
    const int wave = tid >> 6, lane = tid & 63;
    if (lane == 0) redm[wave] = m;
    __syncthreads();
    m = fmaxf(fmaxf(redm[0], redm[1]), fmaxf(redm[2], redm[3]));
    float s = 0.f;
#pragma unroll
    for (int i = 0; i < 4; ++i) {
        v[i][0] = __expf(v[i][0] - m);
        v[i][1] = __expf(v[i][1] - m);
        v[i][2] = __expf(v[i][2] - m);
        v[i][3] = __expf(v[i][3] - m);
        s += v[i][0] + v[i][1] + v[i][2] + v[i][3];
    }
#pragma unroll
    for (int off = 32; off > 0; off >>= 1) s += __shfl_xor(s, off);
    if (lane == 0) reds[wave] = s;
    __syncthreads();
    const float inv = 1.f / (reds[0] + reds[1] + reds[2] + reds[3]);
    bf16x4* outp = (bf16x4*)(attp + (size_t)row * T_);
#pragma unroll
    for (int i = 0; i < 4; ++i) {
        bf16x4 o;
        o[0] = (bf16)(v[i][0] * inv);
        o[1] = (bf16)(v[i][1] * inv);
        o[2] = (bf16)(v[i][2] * inv);
        o[3] = (bf16)(v[i][3] * inv);
        outp[i * 256 + tid] = o;
        // transposed scatter (2B stores, fire-and-forget; 8.4 MB total)
        const int t = (i * 256 + tid) * 4;
#pragma unroll
        for (int c = 0; c < 4; ++c)
            attpT[((size_t)b * T_ + t + c) * K_ + kk_] = o[c];
    }
}

// ---------------- K4: selpT[c,b,e,k](bf16) = sum_{t in chunk c} attp[b,k,t]*xb[b,t,e] ------
// grid (E/64, 8 chunks, B) = 1024 blocks, 256 thr (4 waves). [round-9 proven]
__global__ __launch_bounds__(256) void k4_sel(const bf16* __restrict__ xb,
                                              const bf16* __restrict__ attp,
                                              bf16* __restrict__ selpT) {
    const int eblk = blockIdx.x;
    const int chunk = blockIdx.y;
    const int b = blockIdx.z;
    const int tid = threadIdx.x;
    const int w = tid >> 6, lane = tid & 63, g = lane >> 4, ln = lane & 15;
    const int e0 = eblk * 64;
    const int e = e0 + w * 16 + ln;

    f32x4 acc[8];
#pragma unroll
    for (int m = 0; m < 8; ++m) acc[m] = (f32x4){0.f, 0.f, 0.f, 0.f};

    const int tb = chunk * 512;
#pragma unroll 2
    for (int t0 = 0; t0 < 512; t0 += 32) {
        const int t = tb + t0 + g * 8;
        bf16 xv[8];
#pragma unroll
        for (int j = 0; j < 8; ++j)
            xv[j] = xb[((size_t)b * T_ + t + j) * E_ + e];
        bf16x8 af[8];
#pragma unroll
        for (int m = 0; m < 8; ++m)
            af[m] = *(const bf16x8*)(attp + ((size_t)b * K_ + m * 16 + ln) * T_ + t);
        bf16x8 bf;
#pragma unroll
        for (int j = 0; j < 8; ++j) bf[j] = xv[j];
#pragma unroll
        for (int m = 0; m < 8; ++m)
            acc[m] = __builtin_amdgcn_mfma_f32_16x16x32_bf16(af[m], bf, acc[m], 0, 0, 0);
    }
    __shared__ float tl[64][132];
#pragma unroll
    for (int m = 0; m < 8; ++m)
#pragma unroll
        for (int r = 0; r < 4; ++r)
            tl[w * 16 + ln][m * 16 + g * 4 + r] = acc[m][r];
    __syncthreads();
    bf16* dst = selpT + ((size_t)chunk * B_ + b) * E_ * K_ + (size_t)e0 * K_;
#pragma unroll
    for (int rr = 0; rr < 4; ++rr) {
        const int slot = rr * 256 + tid;
        const int ee = slot >> 4;
        const int kq = slot & 15;
        bf16x8 o;
#pragma unroll
        for (int j = 0; j < 8; ++j) o[j] = (bf16)tl[ee][kq * 8 + j];
        *(bf16x8*)(dst + (size_t)ee * K_ + kq * 8) = o;
    }
}

// ---------------- K4b: flat reduce over 8 chunks -> selbT bf16 [b][e][k] (512 blocks) ----
__global__ __launch_bounds__(256) void k4b_reduce(const bf16* __restrict__ selpT,
                                                  bf16* __restrict__ selbT) {
    const size_t gid = (size_t)blockIdx.x * 256 + threadIdx.x;
    const size_t f = gid * 8;
    float s[8];
#pragma unroll
    for (int j = 0; j < 8; ++j) s[j] = 0.f;
#pragma unroll
    for (int c = 0; c < 8; ++c) {
        bf16x8 v = *(const bf16x8*)(selpT + (size_t)c * (B_ * E_ * K_) + f);
#pragma unroll
        for (int j = 0; j < 8; ++j) s[j] += (float)v[j];
    }
    bf16x8 o;
#pragma unroll
    for (int j = 0; j < 8; ++j) o[j] = (bf16)s[j];
    *(bf16x8*)(selbT + f) = o;
}

// ---------------- K5: out = k*(xb + attpT @ selbT) + b  (no LDS, direct attpT reads) ------
// grid (T/64, E/64, B) = 8192 blocks, 256 thr (4 waves). Wave: 64 t x 16 e, acc[4].
__global__ __launch_bounds__(256) void k5_out(const bf16* __restrict__ xb,
                                              const bf16* __restrict__ attpT,
                                              const bf16* __restrict__ selbT,
                                              const float* __restrict__ kp,
                                              const float* __restrict__ bp,
                                              float* __restrict__ out) {
    const int b = blockIdx.z;
    const int t0 = blockIdx.x * 64;
    const int tid = threadIdx.x;
    const int w = tid >> 6, lane = tid & 63, g = lane >> 4, ln = lane & 15;
    const int e0 = blockIdx.y * 64 + w * 16;
    const float kk = kp[0], bb = bp[0];

    f32x4 acc[4];
#pragma unroll
    for (int m = 0; m < 4; ++m) acc[m] = (f32x4){0.f, 0.f, 0.f, 0.f};

    const bf16* arow = attpT + ((size_t)b * T_ + t0) * K_;
    const bf16* brow = selbT + ((size_t)b * E_ + e0 + ln) * K_;
#pragma unroll
    for (int ks = 0; ks < 4; ++ks) {
        const int k0 = ks * 32 + g * 8;
        bf16x8 bfr = *(const bf16x8*)(brow + k0);
        bf16x8 af[4];
#pragma unroll
        for (int m = 0; m < 4; ++m)
            af[m] = *(const bf16x8*)(arow + (size_t)(m * 16 + ln) * K_ + k0);
#pragma unroll
        for (int m = 0; m < 4; ++m)
            acc[m] = __builtin_amdgcn_mfma_f32_16x16x32_bf16(af[m], bfr, acc[m], 0, 0, 0);
    }
#pragma unroll
    for (int m = 0; m < 4; ++m) {
#pragma unroll
        for (int r = 0; r < 4; ++r) {
            const int t = t0 + m * 16 + g * 4 + r;
            const size_t idx = ((size_t)b * T_ + t) * E_ + e0 + ln;
            out[idx] = kk * ((float)xb[idx] + acc[m][r]) + bb;
        }
    }
}

extern "C" void kernel_launch(void* const* d_in, const int* in_sizes, int n_in,
                              void* d_out, int out_size, void* d_ws, size_t ws_size,
                              hipStream_t stream) {
    const float* x  = (const float*)d_in[0];
    const float* mu = (const float*)d_in[1];
    // d_in[2]=bias, d_in[3]=Wr, d_in[4]=Wl are dead code in the reference forward.
    const float* kp = (const float*)d_in[5];
    const float* bp = (const float*)d_in[6];
    float* out = (float*)d_out;

    char* ws = (char*)d_ws;
    // Region A (33,554,432 B): attP f32 [2][B][K][T] (K1->K2), then reused as
    // selpT bf16 [8][B][E][K] (K4->K4b). Stream-ordered, no overlap hazard.
    float* attP  = (float*)(ws);
    bf16*  selpT = (bf16*)(ws);
    bf16*  attp  = (bf16*)(ws + 33554432);   //  8,388,608
    bf16*  attpT = (bf16*)(ws + 41943040);   //  8,388,608
    bf16*  selbT = (bf16*)(ws + 50331648);   //  2,097,152
    bf16*  mub   = (bf16*)(ws + 52428800);   //    262,144
    bf16*  xb    = (bf16*)(ws + 52690944);   // 67,108,864  (total ~120 MB)

    k0_cvt_mu<<<dim3(512), 256, 0, stream>>>(mu, mub);
    k1_att<<<dim3(64, 2, 8), 256, 0, stream>>>(x, mub, attP, xb);
    k2_softmax<<<dim3(1024), 256, 0, stream>>>(attP, attp, attpT);
    k4_sel<<<dim3(16, 8, 8), 256, 0, stream>>>(xb, attp, selpT);
    k4b_reduce<<<dim3(512), 256, 0, stream>>>(selpT, selbT);
    k5_out<<<dim3(64, 16, 8), 256, 0, stream>>>(xb, attpT, selbT, kp, bp, out);
}

// Round 12
// 232.782 us; speedup vs baseline: 1.2726x; 1.2726x over previous
//
#include <hip/hip_runtime.h>

#define B_ 8
#define T_ 4096
#define E_ 1024
#define K_ 128

typedef __bf16 bf16;
typedef bf16 bf16x8 __attribute__((ext_vector_type(8)));
typedef bf16 bf16x4 __attribute__((ext_vector_type(4)));
typedef float f32x4 __attribute__((ext_vector_type(4)));

// ---------------- K0: convert mu to bf16 ----------------
__global__ __launch_bounds__(256) void k0_cvt_mu(const float* __restrict__ mu,
                                                 bf16* __restrict__ mub) {
    int i = blockIdx.x * 256 + threadIdx.x;
    mub[i] = (bf16)mu[i];
}

// ---------------- K1: attPh[h,b,k,t](bf16) = sum_{e in half h} mu[k,e]*x[b,t,e]; xb=(bf16)x ----
// grid (T/64, 2, B) = 1024 blocks, 256 thr (4 waves). Wave: 16 t x 128 k. [round-9 shape]
__global__ __launch_bounds__(256) void k1_att(const float* __restrict__ x,
                                              const bf16* __restrict__ mub,
                                              bf16* __restrict__ attPh,
                                              bf16* __restrict__ xb) {
    const int b = blockIdx.z;
    const int h = blockIdx.y;
    const int w = threadIdx.x >> 6, lane = threadIdx.x & 63;
    const int g = lane >> 4, ln = lane & 15;
    const int t = blockIdx.x * 64 + w * 16 + ln;

    f32x4 acc[8];
#pragma unroll
    for (int m = 0; m < 8; ++m) acc[m] = (f32x4){0.f, 0.f, 0.f, 0.f};

    const float* xrow = x + ((size_t)b * T_ + t) * E_ + h * 512 + g * 8;
    bf16* xbrow = xb + ((size_t)b * T_ + t) * E_ + h * 512 + g * 8;
    const bf16* mu0 = mub + h * 512 + g * 8;
#pragma unroll 2
    for (int e0 = 0; e0 < 512; e0 += 32) {
        f32x4 u0 = *(const f32x4*)(xrow + e0);
        f32x4 u1 = *(const f32x4*)(xrow + e0 + 4);
        bf16x8 af[8];
#pragma unroll
        for (int m = 0; m < 8; ++m)
            af[m] = *(const bf16x8*)(mu0 + (size_t)(m * 16 + ln) * E_ + e0);
        bf16x8 bf;
        bf[0] = (bf16)u0[0]; bf[1] = (bf16)u0[1]; bf[2] = (bf16)u0[2]; bf[3] = (bf16)u0[3];
        bf[4] = (bf16)u1[0]; bf[5] = (bf16)u1[1]; bf[6] = (bf16)u1[2]; bf[7] = (bf16)u1[3];
        *(bf16x8*)(xbrow + e0) = bf;
#pragma unroll
        for (int m = 0; m < 8; ++m)
            acc[m] = __builtin_amdgcn_mfma_f32_16x16x32_bf16(af[m], bf, acc[m], 0, 0, 0);
    }
#pragma unroll
    for (int m = 0; m < 8; ++m)
#pragma unroll
        for (int r = 0; r < 4; ++r)
            attPh[(((size_t)h * B_ + b) * K_ + m * 16 + g * 4 + r) * T_ + t] =
                (bf16)acc[m][r];
}

// ---------------- K2: fused half-sum + softmax -> attp bf16 (1024 blocks) ----------------
// [round-10 proven body: bf16 half reads, fp32 accumulate]
__global__ __launch_bounds__(256) void k2_softmax(const bf16* __restrict__ attPh,
                                                  bf16* __restrict__ attp) {
    const int row = blockIdx.x;   // b*K + k
    const int tid = threadIdx.x;
    const bf16* p0 = attPh + (size_t)row * T_;
    const bf16* p1 = attPh + (size_t)(B_ * K_) * T_ + (size_t)row * T_;
    float v[16];
    float m = -1e30f;
#pragma unroll
    for (int i = 0; i < 2; ++i) {
        const int off = (i * 256 + tid) * 8;
        bf16x8 a = *(const bf16x8*)(p0 + off);
        bf16x8 c = *(const bf16x8*)(p1 + off);
#pragma unroll
        for (int j = 0; j < 8; ++j) {
            const float val = ((float)a[j] + (float)c[j]) * 0.03125f;
            v[i * 8 + j] = val;
            m = fmaxf(m, val);
        }
    }
#pragma unroll
    for (int off = 32; off > 0; off >>= 1) m = fmaxf(m, __shfl_xor(m, off));
    __shared__ float redm[4], reds[4];
    const int wave = tid >> 6, lane = tid & 63;
    if (lane == 0) redm[wave] = m;
    __syncthreads();
    m = fmaxf(fmaxf(redm[0], redm[1]), fmaxf(redm[2], redm[3]));
    float s = 0.f;
#pragma unroll
    for (int i = 0; i < 16; ++i) {
        v[i] = __expf(v[i] - m);
        s += v[i];
    }
#pragma unroll
    for (int off = 32; off > 0; off >>= 1) s += __shfl_xor(s, off);
    if (lane == 0) reds[wave] = s;
    __syncthreads();
    const float inv = 1.f / (reds[0] + reds[1] + reds[2] + reds[3]);
#pragma unroll
    for (int i = 0; i < 2; ++i) {
        const int off = (i * 256 + tid) * 8;
        bf16x8 o;
#pragma unroll
        for (int j = 0; j < 8; ++j) o[j] = (bf16)(v[i * 8 + j] * inv);
        *(bf16x8*)(attp + (size_t)row * T_ + off) = o;
    }
}

// ---------------- K4: selpT[c,b,e,k](bf16) = sum_{t in chunk c} attp[b,k,t]*xb[b,t,e] ------
// grid (E/64, 8 chunks, B) = 1024 blocks, 256 thr (4 waves). [round-9 proven]
__global__ __launch_bounds__(256) void k4_sel(const bf16* __restrict__ xb,
                                              const bf16* __restrict__ attp,
                                              bf16* __restrict__ selpT) {
    const int eblk = blockIdx.x;
    const int chunk = blockIdx.y;
    const int b = blockIdx.z;
    const int tid = threadIdx.x;
    const int w = tid >> 6, lane = tid & 63, g = lane >> 4, ln = lane & 15;
    const int e0 = eblk * 64;
    const int e = e0 + w * 16 + ln;

    f32x4 acc[8];
#pragma unroll
    for (int m = 0; m < 8; ++m) acc[m] = (f32x4){0.f, 0.f, 0.f, 0.f};

    const int tb = chunk * 512;
#pragma unroll 2
    for (int t0 = 0; t0 < 512; t0 += 32) {
        const int t = tb + t0 + g * 8;
        bf16 xv[8];
#pragma unroll
        for (int j = 0; j < 8; ++j)
            xv[j] = xb[((size_t)b * T_ + t + j) * E_ + e];
        bf16x8 af[8];
#pragma unroll
        for (int m = 0; m < 8; ++m)
            af[m] = *(const bf16x8*)(attp + ((size_t)b * K_ + m * 16 + ln) * T_ + t);
        bf16x8 bf;
#pragma unroll
        for (int j = 0; j < 8; ++j) bf[j] = xv[j];
#pragma unroll
        for (int m = 0; m < 8; ++m)
            acc[m] = __builtin_amdgcn_mfma_f32_16x16x32_bf16(af[m], bf, acc[m], 0, 0, 0);
    }
    __shared__ float tl[64][132];
#pragma unroll
    for (int m = 0; m < 8; ++m)
#pragma unroll
        for (int r = 0; r < 4; ++r)
            tl[w * 16 + ln][m * 16 + g * 4 + r] = acc[m][r];
    __syncthreads();
    bf16* dst = selpT + ((size_t)chunk * B_ + b) * E_ * K_ + (size_t)e0 * K_;
#pragma unroll
    for (int rr = 0; rr < 4; ++rr) {
        const int slot = rr * 256 + tid;
        const int ee = slot >> 4;
        const int kq = slot & 15;
        bf16x8 o;
#pragma unroll
        for (int j = 0; j < 8; ++j) o[j] = (bf16)tl[ee][kq * 8 + j];
        *(bf16x8*)(dst + (size_t)ee * K_ + kq * 8) = o;
    }
}

// ---------------- K4b: flat reduce over 8 chunks -> selbT bf16 [b][e][k] (512 blocks) ----
__global__ __launch_bounds__(256) void k4b_reduce(const bf16* __restrict__ selpT,
                                                  bf16* __restrict__ selbT) {
    const size_t gid = (size_t)blockIdx.x * 256 + threadIdx.x;
    const size_t f = gid * 8;
    float s[8];
#pragma unroll
    for (int j = 0; j < 8; ++j) s[j] = 0.f;
#pragma unroll
    for (int c = 0; c < 8; ++c) {
        bf16x8 v = *(const bf16x8*)(selpT + (size_t)c * (B_ * E_ * K_) + f);
#pragma unroll
        for (int j = 0; j < 8; ++j) s[j] += (float)v[j];
    }
    bf16x8 o;
#pragma unroll
    for (int j = 0; j < 8; ++j) o[j] = (bf16)s[j];
    *(bf16x8*)(selbT + f) = o;
}

// ---------------- K5: out = k*(xb + attp^T @ selbT) + b  (attp transposed in LDS) ----------
// grid (T/64, E/64, B) = 8192 blocks, 256 thr (4 waves). [round-9 proven]
__global__ __launch_bounds__(256) void k5_out(const bf16* __restrict__ xb,
                                              const bf16* __restrict__ attp,
                                              const bf16* __restrict__ selbT,
                                              const float* __restrict__ kp,
                                              const float* __restrict__ bp,
                                              float* __restrict__ out) {
    const int b = blockIdx.z;
    const int t0 = blockIdx.x * 64;
    const int tid = threadIdx.x;
    const int w = tid >> 6, lane = tid & 63, g = lane >> 4, ln = lane & 15;
    const int e0 = blockIdx.y * 64 + w * 16;
    const float kk = kp[0], bb = bp[0];
    __shared__ bf16 pT[64][128];   // (t,k) at pT[t][k ^ ((t&7)<<3)]

    const int u = tid & 3;
    const int kr = tid >> 2;       // 0..63
#pragma unroll
    for (int p = 0; p < 2; ++p) {
        const int k = p * 64 + kr;
        const bf16* src = attp + ((size_t)b * K_ + k) * T_ + t0 + u * 16;
#pragma unroll
        for (int hh = 0; hh < 2; ++hh) {
            bf16x8 v = *(const bf16x8*)(src + hh * 8);
#pragma unroll
            for (int j = 0; j < 8; ++j) {
                const int t = u * 16 + hh * 8 + j;   // t&7 == j
                pT[t][k ^ (j << 3)] = v[j];
            }
        }
    }
    __syncthreads();

    f32x4 acc[4];
#pragma unroll
    for (int m = 0; m < 4; ++m) acc[m] = (f32x4){0.f, 0.f, 0.f, 0.f};

#pragma unroll
    for (int ks = 0; ks < 4; ++ks) {
        const int k0 = ks * 32 + g * 8;
        bf16x8 bfr = *(const bf16x8*)(selbT + ((size_t)b * E_ + e0 + ln) * K_ + k0);
#pragma unroll
        for (int m = 0; m < 4; ++m) {
            const int t = m * 16 + ln;
            bf16x8 af = *(const bf16x8*)&pT[t][k0 ^ ((t & 7) << 3)];
            acc[m] = __builtin_amdgcn_mfma_f32_16x16x32_bf16(af, bfr, acc[m], 0, 0, 0);
        }
    }
#pragma unroll
    for (int m = 0; m < 4; ++m) {
#pragma unroll
        for (int r = 0; r < 4; ++r) {
            const int t = t0 + m * 16 + g * 4 + r;
            const size_t idx = ((size_t)b * T_ + t) * E_ + e0 + ln;
            out[idx] = kk * ((float)xb[idx] + acc[m][r]) + bb;
        }
    }
}

extern "C" void kernel_launch(void* const* d_in, const int* in_sizes, int n_in,
                              void* d_out, int out_size, void* d_ws, size_t ws_size,
                              hipStream_t stream) {
    const float* x  = (const float*)d_in[0];
    const float* mu = (const float*)d_in[1];
    // d_in[2]=bias, d_in[3]=Wr, d_in[4]=Wl are dead code in the reference forward.
    const float* kp = (const float*)d_in[5];
    const float* bp = (const float*)d_in[6];
    float* out = (float*)d_out;

    char* ws = (char*)d_ws;
    // Region A (16,777,216 B): attPh bf16 [2][B][K][T] (K1->K2), then reused as
    // selpT bf16 [8][B][E][K] (K4->K4b). Stream-ordered, no overlap hazard.
    bf16*  attPh = (bf16*)(ws);
    bf16*  selpT = (bf16*)(ws);
    bf16*  attp  = (bf16*)(ws + 16777216);   //  8,388,608
    bf16*  selbT = (bf16*)(ws + 25165824);   //  2,097,152
    bf16*  mub   = (bf16*)(ws + 27262976);   //    262,144
    bf16*  xb    = (bf16*)(ws + 27525120);   // 67,108,864  (total ~94.6 MB)

    k0_cvt_mu<<<dim3(512), 256, 0, stream>>>(mu, mub);
    k1_att<<<dim3(64, 2, 8), 256, 0, stream>>>(x, mub, attPh, xb);
    k2_softmax<<<dim3(1024), 256, 0, stream>>>(attPh, attp);
    k4_sel<<<dim3(16, 8, 8), 256, 0, stream>>>(xb, attp, selpT);
    k4b_reduce<<<dim3(512), 256, 0, stream>>>(selpT, selbT);
    k5_out<<<dim3(64, 16, 8), 256, 0, stream>>>(xb, attp, selbT, kp, bp, out);
}